// Round 1
// baseline (282.239 us; speedup 1.0000x reference)
//
#include <hip/hip_runtime.h>
#include <math.h>

// x: (32,512,2049) fp32 -> out (32,512,1024) fp32
// segments: n_lin (~631) linear, n_cub (~104) cubic, n_tri (~289) tri-max
#define NI 2049
#define ROWS 4
#define WCAP 4096
#define NTRI_MAX 512

// ---------------------------------------------------------------------------
// Pass 1: per tri row, find finite-weight window [start, start+cnt).
// ---------------------------------------------------------------------------
__global__ void logscale_win(const float* __restrict__ w, int n_in,
                             int* __restrict__ tri_start,
                             int* __restrict__ tri_cnt) {
    const int i = blockIdx.x;
    __shared__ int smin, smax;
    if (threadIdx.x == 0) { smin = n_in; smax = -1; }
    __syncthreads();
    int lmin = n_in, lmax = -1;
    const float* wr = w + (size_t)i * n_in;
    for (int b = threadIdx.x; b < n_in; b += blockDim.x) {
        float v = wr[b];
        if (v > -1e30f) { lmin = min(lmin, b); lmax = max(lmax, b); }
    }
    atomicMin(&smin, lmin);
    atomicMax(&smax, lmax);
    __syncthreads();
    if (threadIdx.x == 0) {
        int s = smin, cnt = smax - smin + 1;
        if (cnt < 1) { s = 0; cnt = 1; }
        if (cnt > 64) cnt = 64;          // defensive (real max ~28)
        tri_start[i] = s; tri_cnt[i] = cnt;
    }
}

// ---------------------------------------------------------------------------
// Pass 2 (single block): wave-parallel prefix-sum of tri counts, build fused
// meta[n_out], pack tri weights (one wave per row, coalesced — no binary
// search, no serial scan).
// meta per output o:
//   lin : x=i0 y=i1 z=f
//   cub : x=i0      z=f
//   tri : x=start y=cnt z=off
// ---------------------------------------------------------------------------
__global__ void logscale_pack(const float* __restrict__ w,
                              const float* __restrict__ flin,
                              const float* __restrict__ fcub,
                              const int*   __restrict__ pidx,
                              const int*   __restrict__ tri_start,
                              const int*   __restrict__ tri_cnt,
                              float4* __restrict__ meta,
                              float*  __restrict__ wpk,
                              int*    __restrict__ d_total,
                              int n_lin, int n_cub, int n_tri) {
    __shared__ int offs[NTRI_MAX + 1];
    __shared__ int starts[NTRI_MAX];
    const int tid = threadIdx.x;
    for (int i = tid; i < n_tri; i += blockDim.x) {
        offs[i + 1] = tri_cnt[i];
        starts[i]   = tri_start[i];
    }
    if (tid == 0) offs[0] = 0;
    __syncthreads();

    // wave-0 parallel scan: 64 lanes x 8 serial each covers NTRI_MAX=512
    if (tid < 64) {
        int v[8];
        int run = 0;
        const int base = tid * 8;
        #pragma unroll
        for (int k = 0; k < 8; ++k) {
            int idx = base + k;
            int c = (idx < n_tri) ? offs[idx + 1] : 0;
            run += c;
            v[k] = run;                       // inclusive within chunk
        }
        int tot = run;
        #pragma unroll
        for (int d = 1; d < 64; d <<= 1) {    // Hillis-Steele across lanes
            int up = __shfl_up(tot, (unsigned)d, 64);
            if (tid >= d) tot += up;
        }
        const int excl = tot - run;           // exclusive carry for this chunk
        #pragma unroll
        for (int k = 0; k < 8; ++k) {
            int idx = base + k;
            if (idx < n_tri) offs[idx + 1] = excl + v[k];
        }
    }
    __syncthreads();
    if (tid == 0) {
        int t = offs[n_tri]; if (t > WCAP) t = WCAP;
        *d_total = t;
    }

    const int n_out = n_lin + n_cub + n_tri;
    for (int o = tid; o < n_out; o += blockDim.x) {
        float4 m;
        if (o < n_lin) {
            m.x = __int_as_float(pidx[o]);
            m.y = __int_as_float(pidx[n_lin + o]);
            m.z = flin[o]; m.w = 0.0f;
        } else if (o < n_lin + n_cub) {
            float c = fcub[o - n_lin];
            int i0 = (int)floorf(c);
            m.x = __int_as_float(i0);
            m.y = 0.0f;
            m.z = c - (float)i0; m.w = 0.0f;
        } else {
            int i = o - n_lin - n_cub;
            int oa = min(offs[i], WCAP), ob = min(offs[i + 1], WCAP);
            m.x = __int_as_float(starts[i]);
            m.y = __int_as_float(ob - oa);
            m.z = __int_as_float(oa); m.w = 0.0f;
        }
        meta[o] = m;
    }

    // weight packing: wave wv handles rows wv, wv+4, ... lanes copy one row
    const int wv = tid >> 6, ln = tid & 63;
    for (int i = wv; i < n_tri; i += 4) {
        const int oa = min(offs[i], WCAP);
        const int ob = min(offs[i + 1], WCAP);
        if (ln < ob - oa)
            wpk[oa + ln] = w[(size_t)i * NI + starts[i] + ln];
    }
}

// ---------------------------------------------------------------------------
// Main: ROWS rows per block, LINEAR LDS (no pad — row stride 2049 is odd, so
// no structural stride-32 aliasing; scattered tri gathers conflict ~equally
// with or without swizzle). Linear layout enables float4 staging and lets the
// compiler fold row offsets (8196/16392/24588 B) into ds_read immediates.
// ---------------------------------------------------------------------------
__global__ __launch_bounds__(256) void logscale_main(
    const float*  __restrict__ x,
    const float4* __restrict__ meta,
    const float*  __restrict__ wpk,
    const int*    __restrict__ d_total,
    float* __restrict__ out,
    int n_lin, int n_cub, int n_out, int n_rows) {

    __shared__ __align__(16) float xs[ROWS * NI];   // 8196 floats = 32.8 KB
    __shared__ __align__(16) float wl[WCAP];        // 4096 floats = 16.4 KB

    const int tid  = threadIdx.x;
    const int row0 = blockIdx.x * ROWS;
    const int rows_here = min(ROWS, n_rows - row0);

    // float4 staging: tile base byte offset = row0*NI*4 = 32784*blk ≡ 0 mod 16.
    // rows_here==4 -> nx = 8196 = 2049 float4 exactly (no tail).
    const float* xr = x + (size_t)row0 * NI;
    const int nx = rows_here * NI;
    const int nq = nx >> 2;
    const float4* xr4 = (const float4*)xr;
    float4* xs4 = (float4*)xs;
    for (int i = tid; i < nq; i += 256) xs4[i] = xr4[i];
    for (int i = (nq << 2) + tid; i < nx; i += 256) xs[i] = xr[i];

    const int tw  = *d_total;
    const int twq = (tw + 3) >> 2;                  // wpk is WCAP-sized; over-read safe
    const float4* wp4 = (const float4*)wpk;
    float4* wl4 = (float4*)wl;
    for (int i = tid; i < twq; i += 256) wl4[i] = wp4[i];
    __syncthreads();

    const int n_lc = n_lin + n_cub;
    float* ob = out + (size_t)row0 * n_out;

    if (rows_here == ROWS) {
        for (int o = tid; o < n_out; o += 256) {
            const float4 m = meta[o];
            float res[ROWS];
            if (o < n_lin) {
                const int i0 = __float_as_int(m.x);
                const int i1 = __float_as_int(m.y);
                const float f = m.z;
                #pragma unroll
                for (int r = 0; r < ROWS; ++r) {
                    const int b = r * NI;
                    const float x0 = xs[b + i0];
                    const float x1 = xs[b + i1];
                    res[r] = x0 + f * (x1 - x0);
                }
            } else if (o < n_lc) {
                const int i0 = __float_as_int(m.x);
                const float f = m.z;
                #pragma unroll
                for (int r = 0; r < ROWS; ++r) {
                    const int b = r * NI + i0;
                    const float xm1 = xs[b - 1];
                    const float x0  = xs[b];
                    const float x1  = xs[b + 1];
                    const float x2  = xs[b + 2];
                    res[r] = x0 + 0.5f * f * (x1 - xm1 +
                             f * (2.0f * xm1 - 5.0f * x0 + 4.0f * x1 - x2 +
                             f * (3.0f * (x0 - x1) + x2 - xm1)));
                }
            } else {
                const int s   = __float_as_int(m.x);
                const int cnt = __float_as_int(m.y);
                const int off = __float_as_int(m.z);
                const float* wj = wl + off;
                const float* xp = xs + s;
                float acc0 = -INFINITY, acc1 = -INFINITY;
                float acc2 = -INFINITY, acc3 = -INFINITY;
                for (int j = 0; j < cnt; ++j) {
                    const float wv = wj[j];
                    acc0 = fmaxf(acc0, xp[j] + wv);
                    acc1 = fmaxf(acc1, xp[j + NI] + wv);
                    acc2 = fmaxf(acc2, xp[j + 2 * NI] + wv);
                    acc3 = fmaxf(acc3, xp[j + 3 * NI] + wv);
                }
                res[0] = acc0; res[1] = acc1; res[2] = acc2; res[3] = acc3;
            }
            #pragma unroll
            for (int r = 0; r < ROWS; ++r)
                ob[(size_t)r * n_out + o] = res[r];
        }
    } else {
        for (int o = tid; o < n_out; o += 256) {
            const float4 m = meta[o];
            for (int r = 0; r < rows_here; ++r) {
                const int b = r * NI;
                float res;
                if (o < n_lin) {
                    const int i0 = __float_as_int(m.x);
                    const int i1 = __float_as_int(m.y);
                    const float f = m.z;
                    const float x0 = xs[b + i0];
                    const float x1 = xs[b + i1];
                    res = x0 + f * (x1 - x0);
                } else if (o < n_lc) {
                    const int i0 = __float_as_int(m.x) + b;
                    const float f = m.z;
                    const float xm1 = xs[i0 - 1];
                    const float x0  = xs[i0];
                    const float x1  = xs[i0 + 1];
                    const float x2  = xs[i0 + 2];
                    res = x0 + 0.5f * f * (x1 - xm1 +
                          f * (2.0f * xm1 - 5.0f * x0 + 4.0f * x1 - x2 +
                          f * (3.0f * (x0 - x1) + x2 - xm1)));
                } else {
                    const int s   = __float_as_int(m.x) + b;
                    const int cnt = __float_as_int(m.y);
                    const int off = __float_as_int(m.z);
                    float mx = -INFINITY;
                    for (int j = 0; j < cnt; ++j)
                        mx = fmaxf(mx, xs[s + j] + wl[off + j]);
                    res = mx;
                }
                ob[(size_t)r * n_out + o] = res;
            }
        }
    }
}

extern "C" void kernel_launch(void* const* d_in, const int* in_sizes, int n_in,
                              void* d_out, int out_size, void* d_ws, size_t ws_size,
                              hipStream_t stream) {
    (void)n_in; (void)ws_size; (void)out_size;
    const float* x    = (const float*)d_in[0];
    const float* flin = (const float*)d_in[1];
    const float* fcub = (const float*)d_in[2];
    const float* w    = (const float*)d_in[3];
    const int*   pidx = (const int*)d_in[4];
    float* out = (float*)d_out;

    const int n_lin  = in_sizes[1];
    const int n_cub  = in_sizes[2];
    const int n_tri  = in_sizes[3] / NI;
    const int n_rows = in_sizes[0] / NI;
    const int n_out  = n_lin + n_cub + n_tri;

    // ws layout: meta[n_out] | wpk[WCAP] | tri_start | tri_cnt | total
    float4* meta      = (float4*)d_ws;
    float*  wpk       = (float*)(meta + n_out);
    int*    tri_start = (int*)(wpk + WCAP);
    int*    tri_cnt   = tri_start + NTRI_MAX;
    int*    d_total   = tri_cnt + NTRI_MAX;

    if (n_tri > 0)
        logscale_win<<<n_tri, 256, 0, stream>>>(w, NI, tri_start, tri_cnt);
    logscale_pack<<<1, 256, 0, stream>>>(w, flin, fcub, pidx, tri_start, tri_cnt,
                                         meta, wpk, d_total, n_lin, n_cub, n_tri);
    const int nblk = (n_rows + ROWS - 1) / ROWS;
    logscale_main<<<nblk, 256, 0, stream>>>(x, meta, wpk, d_total, out,
                                            n_lin, n_cub, n_out, n_rows);
}

// Round 2
// 273.349 us; speedup vs baseline: 1.0325x; 1.0325x over previous
//
#include <hip/hip_runtime.h>
#include <math.h>

// x: (32,512,2049) fp32 -> out (32,512,1024) fp32
// segments: n_lin (~631) linear, n_cub (~104) cubic, n_tri (~289) tri-max
#define NI 2049
#define ROWS 4
#define BT 512              // threads per block (8 waves)
#define WCAP 4096
#define NTRI_MAX 512

// ---------------------------------------------------------------------------
// Pass 1: per tri row, find finite-weight window [start, start+cnt).
// ---------------------------------------------------------------------------
__global__ void logscale_win(const float* __restrict__ w, int n_in,
                             int* __restrict__ tri_start,
                             int* __restrict__ tri_cnt) {
    const int i = blockIdx.x;
    __shared__ int smin, smax;
    if (threadIdx.x == 0) { smin = n_in; smax = -1; }
    __syncthreads();
    int lmin = n_in, lmax = -1;
    const float* wr = w + (size_t)i * n_in;
    for (int b = threadIdx.x; b < n_in; b += blockDim.x) {
        float v = wr[b];
        if (v > -1e30f) { lmin = min(lmin, b); lmax = max(lmax, b); }
    }
    atomicMin(&smin, lmin);
    atomicMax(&smax, lmax);
    __syncthreads();
    if (threadIdx.x == 0) {
        int s = smin, cnt = smax - smin + 1;
        if (cnt < 1) { s = 0; cnt = 1; }
        if (cnt > 64) cnt = 64;          // defensive (real max ~28)
        tri_start[i] = s; tri_cnt[i] = cnt;
    }
}

// ---------------------------------------------------------------------------
// Pass 2 (single block): wave-parallel prefix-sum of tri counts, build fused
// meta[n_out], pack tri weights (one wave per row, coalesced).
// meta per output o:
//   lin : x=i0 y=i1 z=f
//   cub : x=i0      z=f
//   tri : x=start y=cnt z=off
// ---------------------------------------------------------------------------
__global__ void logscale_pack(const float* __restrict__ w,
                              const float* __restrict__ flin,
                              const float* __restrict__ fcub,
                              const int*   __restrict__ pidx,
                              const int*   __restrict__ tri_start,
                              const int*   __restrict__ tri_cnt,
                              float4* __restrict__ meta,
                              float*  __restrict__ wpk,
                              int*    __restrict__ d_total,
                              int n_lin, int n_cub, int n_tri) {
    __shared__ int offs[NTRI_MAX + 1];
    __shared__ int starts[NTRI_MAX];
    const int tid = threadIdx.x;
    for (int i = tid; i < n_tri; i += blockDim.x) {
        offs[i + 1] = tri_cnt[i];
        starts[i]   = tri_start[i];
    }
    if (tid == 0) offs[0] = 0;
    __syncthreads();

    // wave-0 parallel scan: 64 lanes x 8 serial each covers NTRI_MAX=512
    if (tid < 64) {
        int v[8];
        int run = 0;
        const int base = tid * 8;
        #pragma unroll
        for (int k = 0; k < 8; ++k) {
            int idx = base + k;
            int c = (idx < n_tri) ? offs[idx + 1] : 0;
            run += c;
            v[k] = run;                       // inclusive within chunk
        }
        int tot = run;
        #pragma unroll
        for (int d = 1; d < 64; d <<= 1) {    // Hillis-Steele across lanes
            int up = __shfl_up(tot, (unsigned)d, 64);
            if (tid >= d) tot += up;
        }
        const int excl = tot - run;           // exclusive carry for this chunk
        #pragma unroll
        for (int k = 0; k < 8; ++k) {
            int idx = base + k;
            if (idx < n_tri) offs[idx + 1] = excl + v[k];
        }
    }
    __syncthreads();
    if (tid == 0) {
        int t = offs[n_tri]; if (t > WCAP) t = WCAP;
        *d_total = t;
    }

    const int n_out = n_lin + n_cub + n_tri;
    for (int o = tid; o < n_out; o += blockDim.x) {
        float4 m;
        if (o < n_lin) {
            m.x = __int_as_float(pidx[o]);
            m.y = __int_as_float(pidx[n_lin + o]);
            m.z = flin[o]; m.w = 0.0f;
        } else if (o < n_lin + n_cub) {
            float c = fcub[o - n_lin];
            int i0 = (int)floorf(c);
            m.x = __int_as_float(i0);
            m.y = 0.0f;
            m.z = c - (float)i0; m.w = 0.0f;
        } else {
            int i = o - n_lin - n_cub;
            int oa = min(offs[i], WCAP), ob = min(offs[i + 1], WCAP);
            m.x = __int_as_float(starts[i]);
            m.y = __int_as_float(ob - oa);
            m.z = __int_as_float(oa); m.w = 0.0f;
        }
        meta[o] = m;
    }

    // weight packing: wave wv handles rows wv, wv+4, ... lanes copy one row
    const int wv = tid >> 6, ln = tid & 63;
    for (int i = wv; i < n_tri; i += 4) {
        const int oa = min(offs[i], WCAP);
        const int ob = min(offs[i + 1], WCAP);
        if (ln < ob - oa)
            wpk[oa + ln] = w[(size_t)i * NI + starts[i] + ln];
    }
}

// ---------------------------------------------------------------------------
// Per-output compute for a full ROWS tile.
// ---------------------------------------------------------------------------
__device__ __forceinline__ void compute_rows4(
    int o, float4 m, const float* __restrict__ xs, const float* __restrict__ wl,
    int n_lin, int n_lc, float res[ROWS]) {
    if (o < n_lin) {
        const int i0 = __float_as_int(m.x);
        const int i1 = __float_as_int(m.y);
        const float f = m.z;
        #pragma unroll
        for (int r = 0; r < ROWS; ++r) {
            const int b = r * NI;
            const float x0 = xs[b + i0];
            const float x1 = xs[b + i1];
            res[r] = x0 + f * (x1 - x0);
        }
    } else if (o < n_lc) {
        const int i0 = __float_as_int(m.x);
        const float f = m.z;
        #pragma unroll
        for (int r = 0; r < ROWS; ++r) {
            const int b = r * NI + i0;
            const float xm1 = xs[b - 1];
            const float x0  = xs[b];
            const float x1  = xs[b + 1];
            const float x2  = xs[b + 2];
            res[r] = x0 + 0.5f * f * (x1 - xm1 +
                     f * (2.0f * xm1 - 5.0f * x0 + 4.0f * x1 - x2 +
                     f * (3.0f * (x0 - x1) + x2 - xm1)));
        }
    } else {
        const int s   = __float_as_int(m.x);
        const int cnt = __float_as_int(m.y);
        const int off = __float_as_int(m.z);
        const float* wj = wl + off;
        const float* xp = xs + s;
        float acc0 = -INFINITY, acc1 = -INFINITY;
        float acc2 = -INFINITY, acc3 = -INFINITY;
        for (int j = 0; j < cnt; ++j) {
            const float wv = wj[j];
            acc0 = fmaxf(acc0, xp[j] + wv);
            acc1 = fmaxf(acc1, xp[j + NI] + wv);
            acc2 = fmaxf(acc2, xp[j + 2 * NI] + wv);
            acc3 = fmaxf(acc3, xp[j + 3 * NI] + wv);
        }
        res[0] = acc0; res[1] = acc1; res[2] = acc2; res[3] = acc3;
    }
}

// ---------------------------------------------------------------------------
// Main: ROWS rows per block, 512 threads (8 waves). LDS 48.5 KB -> 3
// blocks/CU -> 24 waves/CU (75%), vs 12 waves with 256-thread blocks.
// Latency-bound kernel (VALUBusy 10%, HBM 19%) -> more TLP is the lever.
// Metas for both o-iterations prefetched into registers before the staging
// barrier so their L2 latency hides under staging.
// ---------------------------------------------------------------------------
__global__ __launch_bounds__(BT, 6) void logscale_main(
    const float*  __restrict__ x,
    const float4* __restrict__ meta,
    const float*  __restrict__ wpk,
    const int*    __restrict__ d_total,
    float* __restrict__ out,
    int n_lin, int n_cub, int n_out, int n_rows) {

    __shared__ __align__(16) float xs[ROWS * NI];   // 8196 floats = 32.8 KB
    __shared__ __align__(16) float wl[WCAP];        // 4096 floats = 16.4 KB

    const int tid  = threadIdx.x;
    const int row0 = blockIdx.x * ROWS;
    const int rows_here = min(ROWS, n_rows - row0);

    // prefetch metas (issued before staging; consumed after the barrier)
    const int o0 = tid, o1 = tid + BT;
    float4 m0 = make_float4(0.f, 0.f, 0.f, 0.f), m1 = m0;
    if (o0 < n_out) m0 = meta[o0];
    if (o1 < n_out) m1 = meta[o1];

    // float4 staging: tile base byte offset = row0*NI*4 = 32784*blk ≡ 0 mod 16.
    // rows_here==4 -> nx = 8196 floats = 2049 float4 exactly (no tail).
    const float* xr = x + (size_t)row0 * NI;
    const int nx = rows_here * NI;
    const int nq = nx >> 2;
    const float4* xr4 = (const float4*)xr;
    float4* xs4 = (float4*)xs;
    for (int i = tid; i < nq; i += BT) xs4[i] = xr4[i];
    for (int i = (nq << 2) + tid; i < nx; i += BT) xs[i] = xr[i];

    const int tw  = *d_total;
    const int twq = (tw + 3) >> 2;                  // wpk is WCAP-sized; over-read safe
    const float4* wp4 = (const float4*)wpk;
    float4* wl4 = (float4*)wl;
    for (int i = tid; i < twq; i += BT) wl4[i] = wp4[i];
    __syncthreads();

    const int n_lc = n_lin + n_cub;
    float* ob = out + (size_t)row0 * n_out;

    if (rows_here == ROWS) {
        float res[ROWS];
        if (o0 < n_out) {
            compute_rows4(o0, m0, xs, wl, n_lin, n_lc, res);
            #pragma unroll
            for (int r = 0; r < ROWS; ++r) ob[(size_t)r * n_out + o0] = res[r];
        }
        if (o1 < n_out) {
            compute_rows4(o1, m1, xs, wl, n_lin, n_lc, res);
            #pragma unroll
            for (int r = 0; r < ROWS; ++r) ob[(size_t)r * n_out + o1] = res[r];
        }
        for (int o = tid + 2 * BT; o < n_out; o += BT) {   // generic fallback
            const float4 m = meta[o];
            compute_rows4(o, m, xs, wl, n_lin, n_lc, res);
            #pragma unroll
            for (int r = 0; r < ROWS; ++r) ob[(size_t)r * n_out + o] = res[r];
        }
    } else {
        for (int o = tid; o < n_out; o += BT) {
            const float4 m = meta[o];
            for (int r = 0; r < rows_here; ++r) {
                const int b = r * NI;
                float res;
                if (o < n_lin) {
                    const int i0 = __float_as_int(m.x);
                    const int i1 = __float_as_int(m.y);
                    const float f = m.z;
                    const float x0 = xs[b + i0];
                    const float x1 = xs[b + i1];
                    res = x0 + f * (x1 - x0);
                } else if (o < n_lc) {
                    const int i0 = __float_as_int(m.x) + b;
                    const float f = m.z;
                    const float xm1 = xs[i0 - 1];
                    const float x0  = xs[i0];
                    const float x1  = xs[i0 + 1];
                    const float x2  = xs[i0 + 2];
                    res = x0 + 0.5f * f * (x1 - xm1 +
                          f * (2.0f * xm1 - 5.0f * x0 + 4.0f * x1 - x2 +
                          f * (3.0f * (x0 - x1) + x2 - xm1)));
                } else {
                    const int s   = __float_as_int(m.x) + b;
                    const int cnt = __float_as_int(m.y);
                    const int off = __float_as_int(m.z);
                    float mx = -INFINITY;
                    for (int j = 0; j < cnt; ++j)
                        mx = fmaxf(mx, xs[s + j] + wl[off + j]);
                    res = mx;
                }
                ob[(size_t)r * n_out + o] = res;
            }
        }
    }
}

extern "C" void kernel_launch(void* const* d_in, const int* in_sizes, int n_in,
                              void* d_out, int out_size, void* d_ws, size_t ws_size,
                              hipStream_t stream) {
    (void)n_in; (void)ws_size; (void)out_size;
    const float* x    = (const float*)d_in[0];
    const float* flin = (const float*)d_in[1];
    const float* fcub = (const float*)d_in[2];
    const float* w    = (const float*)d_in[3];
    const int*   pidx = (const int*)d_in[4];
    float* out = (float*)d_out;

    const int n_lin  = in_sizes[1];
    const int n_cub  = in_sizes[2];
    const int n_tri  = in_sizes[3] / NI;
    const int n_rows = in_sizes[0] / NI;
    const int n_out  = n_lin + n_cub + n_tri;

    // ws layout: meta[n_out] | wpk[WCAP] | tri_start | tri_cnt | total
    float4* meta      = (float4*)d_ws;
    float*  wpk       = (float*)(meta + n_out);
    int*    tri_start = (int*)(wpk + WCAP);
    int*    tri_cnt   = tri_start + NTRI_MAX;
    int*    d_total   = tri_cnt + NTRI_MAX;

    if (n_tri > 0)
        logscale_win<<<n_tri, 256, 0, stream>>>(w, NI, tri_start, tri_cnt);
    logscale_pack<<<1, 256, 0, stream>>>(w, flin, fcub, pidx, tri_start, tri_cnt,
                                         meta, wpk, d_total, n_lin, n_cub, n_tri);
    const int nblk = (n_rows + ROWS - 1) / ROWS;
    logscale_main<<<nblk, BT, 0, stream>>>(x, meta, wpk, d_total, out,
                                           n_lin, n_cub, n_out, n_rows);
}

// Round 3
// 258.804 us; speedup vs baseline: 1.0905x; 1.0562x over previous
//
#include <hip/hip_runtime.h>
#include <math.h>

// x: (32,512,2049) fp32 -> out (32,512,1024) fp32
// segments: n_lin (~631) linear, n_cub (~104) cubic, n_tri (~289) tri-max
#define NI 2049
#define ROWS 4
#define BT 1024             // threads per block (16 waves); n_out==BT -> 1 output/thread
#define WCAP 4096
#define NTRI_MAX 512

// ---------------------------------------------------------------------------
// Pass 1: per tri row, find finite-weight window [start, start+cnt).
// ---------------------------------------------------------------------------
__global__ void logscale_win(const float* __restrict__ w, int n_in,
                             int* __restrict__ tri_start,
                             int* __restrict__ tri_cnt) {
    const int i = blockIdx.x;
    __shared__ int smin, smax;
    if (threadIdx.x == 0) { smin = n_in; smax = -1; }
    __syncthreads();
    int lmin = n_in, lmax = -1;
    const float* wr = w + (size_t)i * n_in;
    for (int b = threadIdx.x; b < n_in; b += blockDim.x) {
        float v = wr[b];
        if (v > -1e30f) { lmin = min(lmin, b); lmax = max(lmax, b); }
    }
    atomicMin(&smin, lmin);
    atomicMax(&smax, lmax);
    __syncthreads();
    if (threadIdx.x == 0) {
        int s = smin, cnt = smax - smin + 1;
        if (cnt < 1) { s = 0; cnt = 1; }
        if (cnt > 64) cnt = 64;          // defensive (real max ~28)
        tri_start[i] = s; tri_cnt[i] = cnt;
    }
}

// ---------------------------------------------------------------------------
// Pass 2 (single block): wave-parallel prefix-sum of tri counts, build fused
// meta[n_out], pack tri weights (one wave per row, coalesced).
// meta per output o:
//   lin : x=i0 y=i1 z=f
//   cub : x=i0      z=f
//   tri : x=start y=cnt z=off
// ---------------------------------------------------------------------------
__global__ void logscale_pack(const float* __restrict__ w,
                              const float* __restrict__ flin,
                              const float* __restrict__ fcub,
                              const int*   __restrict__ pidx,
                              const int*   __restrict__ tri_start,
                              const int*   __restrict__ tri_cnt,
                              float4* __restrict__ meta,
                              float*  __restrict__ wpk,
                              int*    __restrict__ d_total,
                              int n_lin, int n_cub, int n_tri) {
    __shared__ int offs[NTRI_MAX + 1];
    __shared__ int starts[NTRI_MAX];
    const int tid = threadIdx.x;
    for (int i = tid; i < n_tri; i += blockDim.x) {
        offs[i + 1] = tri_cnt[i];
        starts[i]   = tri_start[i];
    }
    if (tid == 0) offs[0] = 0;
    __syncthreads();

    // wave-0 parallel scan: 64 lanes x 8 serial each covers NTRI_MAX=512
    if (tid < 64) {
        int v[8];
        int run = 0;
        const int base = tid * 8;
        #pragma unroll
        for (int k = 0; k < 8; ++k) {
            int idx = base + k;
            int c = (idx < n_tri) ? offs[idx + 1] : 0;
            run += c;
            v[k] = run;                       // inclusive within chunk
        }
        int tot = run;
        #pragma unroll
        for (int d = 1; d < 64; d <<= 1) {    // Hillis-Steele across lanes
            int up = __shfl_up(tot, (unsigned)d, 64);
            if (tid >= d) tot += up;
        }
        const int excl = tot - run;           // exclusive carry for this chunk
        #pragma unroll
        for (int k = 0; k < 8; ++k) {
            int idx = base + k;
            if (idx < n_tri) offs[idx + 1] = excl + v[k];
        }
    }
    __syncthreads();
    if (tid == 0) {
        int t = offs[n_tri]; if (t > WCAP) t = WCAP;
        *d_total = t;
    }

    const int n_out = n_lin + n_cub + n_tri;
    for (int o = tid; o < n_out; o += blockDim.x) {
        float4 m;
        if (o < n_lin) {
            m.x = __int_as_float(pidx[o]);
            m.y = __int_as_float(pidx[n_lin + o]);
            m.z = flin[o]; m.w = 0.0f;
        } else if (o < n_lin + n_cub) {
            float c = fcub[o - n_lin];
            int i0 = (int)floorf(c);
            m.x = __int_as_float(i0);
            m.y = 0.0f;
            m.z = c - (float)i0; m.w = 0.0f;
        } else {
            int i = o - n_lin - n_cub;
            int oa = min(offs[i], WCAP), ob = min(offs[i + 1], WCAP);
            m.x = __int_as_float(starts[i]);
            m.y = __int_as_float(ob - oa);
            m.z = __int_as_float(oa); m.w = 0.0f;
        }
        meta[o] = m;
    }

    // weight packing: wave wv handles rows wv, wv+4, ... lanes copy one row
    const int wv = tid >> 6, ln = tid & 63;
    for (int i = wv; i < n_tri; i += 4) {
        const int oa = min(offs[i], WCAP);
        const int ob = min(offs[i + 1], WCAP);
        if (ln < ob - oa)
            wpk[oa + ln] = w[(size_t)i * NI + starts[i] + ln];
    }
}

// ---------------------------------------------------------------------------
// Per-output compute for a full ROWS tile.
// ---------------------------------------------------------------------------
__device__ __forceinline__ void compute_rows4(
    int o, float4 m, const float* __restrict__ xs, const float* __restrict__ wl,
    int n_lin, int n_lc, float res[ROWS]) {
    if (o < n_lin) {
        const int i0 = __float_as_int(m.x);
        const int i1 = __float_as_int(m.y);
        const float f = m.z;
        #pragma unroll
        for (int r = 0; r < ROWS; ++r) {
            const int b = r * NI;
            const float x0 = xs[b + i0];
            const float x1 = xs[b + i1];
            res[r] = x0 + f * (x1 - x0);
        }
    } else if (o < n_lc) {
        const int i0 = __float_as_int(m.x);
        const float f = m.z;
        #pragma unroll
        for (int r = 0; r < ROWS; ++r) {
            const int b = r * NI + i0;
            const float xm1 = xs[b - 1];
            const float x0  = xs[b];
            const float x1  = xs[b + 1];
            const float x2  = xs[b + 2];
            res[r] = x0 + 0.5f * f * (x1 - xm1 +
                     f * (2.0f * xm1 - 5.0f * x0 + 4.0f * x1 - x2 +
                     f * (3.0f * (x0 - x1) + x2 - xm1)));
        }
    } else {
        const int s   = __float_as_int(m.x);
        const int cnt = __float_as_int(m.y);
        const int off = __float_as_int(m.z);
        const float* wj = wl + off;
        const float* xp = xs + s;
        float acc0 = -INFINITY, acc1 = -INFINITY;
        float acc2 = -INFINITY, acc3 = -INFINITY;
        for (int j = 0; j < cnt; ++j) {
            const float wv = wj[j];
            acc0 = fmaxf(acc0, xp[j] + wv);
            acc1 = fmaxf(acc1, xp[j + NI] + wv);
            acc2 = fmaxf(acc2, xp[j + 2 * NI] + wv);
            acc3 = fmaxf(acc3, xp[j + 3 * NI] + wv);
        }
        res[0] = acc0; res[1] = acc1; res[2] = acc2; res[3] = acc3;
    }
}

// ---------------------------------------------------------------------------
// Main: ROWS=4 rows per block, 1024 threads (16 waves). LDS 48.5 KB -> 2
// blocks/CU -> 32 waves/CU = 100% of wave cap (vs 16 at BT=512), with
// UNCHANGED per-block meta/wl traffic and amortization. Latency-bound kernel
// (all pipes <25%) -> maximize TLP at zero memory cost. n_out==BT -> each
// thread owns exactly one output; meta prefetched before the staging barrier.
// VGPR=40 fits the 64-VGPR/8-waves-per-SIMD budget.
// ---------------------------------------------------------------------------
__global__ __launch_bounds__(BT, 8) void logscale_main(
    const float*  __restrict__ x,
    const float4* __restrict__ meta,
    const float*  __restrict__ wpk,
    const int*    __restrict__ d_total,
    float* __restrict__ out,
    int n_lin, int n_cub, int n_out, int n_rows) {

    __shared__ __align__(16) float xs[ROWS * NI];   // 8196 floats = 32.8 KB
    __shared__ __align__(16) float wl[WCAP];        // 4096 floats = 16.4 KB

    const int tid  = threadIdx.x;
    const int row0 = blockIdx.x * ROWS;
    const int rows_here = min(ROWS, n_rows - row0);

    // prefetch meta (issued before staging; consumed after the barrier)
    float4 m0 = make_float4(0.f, 0.f, 0.f, 0.f);
    if (tid < n_out) m0 = meta[tid];

    // float4 staging: tile base byte offset = row0*NI*4 = 32784*blk ≡ 0 mod 16.
    // rows_here==4 -> nx = 8196 floats = 2049 float4 exactly (no tail).
    const float* xr = x + (size_t)row0 * NI;
    const int nx = rows_here * NI;
    const int nq = nx >> 2;
    const float4* xr4 = (const float4*)xr;
    float4* xs4 = (float4*)xs;
    for (int i = tid; i < nq; i += BT) xs4[i] = xr4[i];
    for (int i = (nq << 2) + tid; i < nx; i += BT) xs[i] = xr[i];

    const int tw  = *d_total;
    const int twq = (tw + 3) >> 2;                  // wpk is WCAP-sized; over-read safe
    const float4* wp4 = (const float4*)wpk;
    float4* wl4 = (float4*)wl;
    for (int i = tid; i < twq; i += BT) wl4[i] = wp4[i];
    __syncthreads();

    const int n_lc = n_lin + n_cub;
    float* ob = out + (size_t)row0 * n_out;

    if (rows_here == ROWS) {
        float res[ROWS];
        if (tid < n_out) {
            compute_rows4(tid, m0, xs, wl, n_lin, n_lc, res);
            #pragma unroll
            for (int r = 0; r < ROWS; ++r) ob[(size_t)r * n_out + tid] = res[r];
        }
        for (int o = tid + BT; o < n_out; o += BT) {   // generic fallback (n_out > BT)
            const float4 m = meta[o];
            compute_rows4(o, m, xs, wl, n_lin, n_lc, res);
            #pragma unroll
            for (int r = 0; r < ROWS; ++r) ob[(size_t)r * n_out + o] = res[r];
        }
    } else {
        for (int o = tid; o < n_out; o += BT) {
            const float4 m = meta[o];
            for (int r = 0; r < rows_here; ++r) {
                const int b = r * NI;
                float res;
                if (o < n_lin) {
                    const int i0 = __float_as_int(m.x);
                    const int i1 = __float_as_int(m.y);
                    const float f = m.z;
                    const float x0 = xs[b + i0];
                    const float x1 = xs[b + i1];
                    res = x0 + f * (x1 - x0);
                } else if (o < n_lc) {
                    const int i0 = __float_as_int(m.x) + b;
                    const float f = m.z;
                    const float xm1 = xs[i0 - 1];
                    const float x0  = xs[i0];
                    const float x1  = xs[i0 + 1];
                    const float x2  = xs[i0 + 2];
                    res = x0 + 0.5f * f * (x1 - xm1 +
                          f * (2.0f * xm1 - 5.0f * x0 + 4.0f * x1 - x2 +
                          f * (3.0f * (x0 - x1) + x2 - xm1)));
                } else {
                    const int s   = __float_as_int(m.x) + b;
                    const int cnt = __float_as_int(m.y);
                    const int off = __float_as_int(m.z);
                    float mx = -INFINITY;
                    for (int j = 0; j < cnt; ++j)
                        mx = fmaxf(mx, xs[s + j] + wl[off + j]);
                    res = mx;
                }
                ob[(size_t)r * n_out + o] = res;
            }
        }
    }
}

extern "C" void kernel_launch(void* const* d_in, const int* in_sizes, int n_in,
                              void* d_out, int out_size, void* d_ws, size_t ws_size,
                              hipStream_t stream) {
    (void)n_in; (void)ws_size; (void)out_size;
    const float* x    = (const float*)d_in[0];
    const float* flin = (const float*)d_in[1];
    const float* fcub = (const float*)d_in[2];
    const float* w    = (const float*)d_in[3];
    const int*   pidx = (const int*)d_in[4];
    float* out = (float*)d_out;

    const int n_lin  = in_sizes[1];
    const int n_cub  = in_sizes[2];
    const int n_tri  = in_sizes[3] / NI;
    const int n_rows = in_sizes[0] / NI;
    const int n_out  = n_lin + n_cub + n_tri;

    // ws layout: meta[n_out] | wpk[WCAP] | tri_start | tri_cnt | total
    float4* meta      = (float4*)d_ws;
    float*  wpk       = (float*)(meta + n_out);
    int*    tri_start = (int*)(wpk + WCAP);
    int*    tri_cnt   = tri_start + NTRI_MAX;
    int*    d_total   = tri_cnt + NTRI_MAX;

    if (n_tri > 0)
        logscale_win<<<n_tri, 256, 0, stream>>>(w, NI, tri_start, tri_cnt);
    logscale_pack<<<1, 256, 0, stream>>>(w, flin, fcub, pidx, tri_start, tri_cnt,
                                         meta, wpk, d_total, n_lin, n_cub, n_tri);
    const int nblk = (n_rows + ROWS - 1) / ROWS;
    logscale_main<<<nblk, BT, 0, stream>>>(x, meta, wpk, d_total, out,
                                           n_lin, n_cub, n_out, n_rows);
}